// Round 3
// baseline (547.789 us; speedup 1.0000x reference)
//
#include <hip/hip_runtime.h>
#include <hip/hip_bf16.h>

// ---------------------------------------------------------------------------
// AfmoE MoE: routing (sigmoid top-8) + 16 routed SwiGLU experts + shared
// expert as expert #16 via gather lists.
// Round 2: double-buffered global_load_lds K-loop (1 barrier/step, loads
// issued after the barrier so they overlap MFMA of the previous tile).
// ---------------------------------------------------------------------------

typedef __attribute__((ext_vector_type(8))) short bf16x8;
typedef __attribute__((ext_vector_type(4))) float f32x4;

#define NTOK 1024   // B*S
#define DD   1024   // hidden
#define II   1024   // intermediate (same for shared)
#define NE   16     // routed experts
#define NEXP 17     // + shared expert as index 16
#define KSEL 8
#define RSCALE 2.826f

// GEMM tiling
#define BM 128
#define BN 64
#define BK 32
#define LDA 40      // fallback-path LDS stride
#define AHALF (BM * BK)   // 4096 elems per A buffer
#define BHALF (BN * BK)   // 2048 elems per B buffer

// workspace layout (bytes)
#define MB (1024ull*1024ull)
#define OFF_XBF   0ull                         // ushort[NTOK*DD]          2 MiB
#define OFF_H     (2ull*MB)                    // ushort[NEXP*NTOK*II]    34 MiB
#define OFF_WG    (36ull*MB)                   // ushort[NEXP*II*DD]      34 MiB
#define OFF_WU    (70ull*MB)                   // ushort[NEXP*II*DD]      34 MiB
#define OFF_WD    (104ull*MB)                  // ushort[NEXP*DD*II]      34 MiB
#define OFF_LIST  (138ull*MB)                  // int[NEXP*NTOK]
#define OFF_SCALE (OFF_LIST + 4ull*NEXP*NTOK)  // float[NEXP*NTOK]
#define OFF_CNT   (OFF_SCALE + 4ull*NEXP*NTOK) // int[NEXP]
#define WS_NEED   (OFF_CNT + 4096ull)

__device__ __forceinline__ unsigned short f2bf(float f) {
    union { __hip_bfloat16 h; unsigned short u; } c;
    c.h = __float2bfloat16(f);
    return c.u;
}

__device__ __forceinline__ void gl2lds16(const unsigned short* g, unsigned short* l) {
    __builtin_amdgcn_global_load_lds(
        (const __attribute__((address_space(1))) void*)g,
        (__attribute__((address_space(3))) void*)l, 16, 0, 0);
}

// --- convert x to bf16; init shared-expert list/scale/count -----------------
__global__ __launch_bounds__(256) void prep_kernel(
    const float* __restrict__ x, unsigned short* __restrict__ xbf,
    int* __restrict__ list, float* __restrict__ scalebuf, int* __restrict__ count)
{
    int idx = blockIdx.x * 256 + threadIdx.x;
    float4 v = ((const float4*)x)[idx];
    ((ushort4*)xbf)[idx] = make_ushort4(f2bf(v.x), f2bf(v.y), f2bf(v.z), f2bf(v.w));
    if (idx < NTOK) { list[NE * NTOK + idx] = idx; scalebuf[NE * NTOK + idx] = 1.0f; }
    if (idx == 0) count[NE] = NTOK;
}

// --- convert all expert weights fp32 -> bf16 pools -------------------------
__global__ __launch_bounds__(256) void wconv_kernel(
    const float* __restrict__ wg, const float* __restrict__ wu, const float* __restrict__ wd,
    const float* __restrict__ sgw, const float* __restrict__ suw, const float* __restrict__ sdw,
    unsigned short* __restrict__ wgb, unsigned short* __restrict__ wub,
    unsigned short* __restrict__ wdb)
{
    size_t i4 = (size_t)blockIdx.x * 256 + threadIdx.x;
    const size_t ROUTED4 = (size_t)NE * II * DD / 4;
    int p = blockIdx.y;
    const float* rsrc = (p == 0) ? wg : (p == 1) ? wu : wd;
    const float* ssrc = (p == 0) ? sgw : (p == 1) ? suw : sdw;
    unsigned short* dst = (p == 0) ? wgb : (p == 1) ? wub : wdb;
    const float* src = (i4 < ROUTED4) ? rsrc + 4 * i4 : ssrc + 4 * (i4 - ROUTED4);
    float4 v = *(const float4*)src;
    ((ushort4*)dst)[i4] = make_ushort4(f2bf(v.x), f2bf(v.y), f2bf(v.z), f2bf(v.w));
}

// --- routing: one wave per token -------------------------------------------
__global__ __launch_bounds__(64) void routing_kernel(
    const float* __restrict__ x, const float* __restrict__ gw,
    const float* __restrict__ bias, int* __restrict__ count,
    int* __restrict__ list, float* __restrict__ scalebuf)
{
    int t = blockIdx.x, lane = threadIdx.x;
    float acc[NE];
#pragma unroll
    for (int e = 0; e < NE; e++) acc[e] = 0.f;
    const float* xr = x + (size_t)t * DD;
    for (int i = 0; i < DD / 64; i++) {
        float xv = xr[lane + 64 * i];
#pragma unroll
        for (int e = 0; e < NE; e++) acc[e] += xv * gw[e * DD + lane + 64 * i];
    }
#pragma unroll
    for (int e = 0; e < NE; e++) {
        float v = acc[e];
        for (int off = 32; off > 0; off >>= 1) v += __shfl_xor(v, off, 64);
        acc[e] = v;
    }
    if (lane == 0) {
        float sc[NE], sel[NE];
#pragma unroll
        for (int e = 0; e < NE; e++) {
            sc[e] = 1.f / (1.f + expf(-acc[e]));
            sel[e] = sc[e] + bias[e];
        }
        bool used[NE] = {};
        int inds[KSEL];
        float ssum = 0.f;
        for (int k = 0; k < KSEL; k++) {
            float best = -1e30f; int bi = 0;
            for (int e = 0; e < NE; e++)
                if (!used[e] && sel[e] > best) { best = sel[e]; bi = e; }
            used[bi] = true; inds[k] = bi; ssum += sc[bi];
        }
        float inv = RSCALE / ssum;
        for (int k = 0; k < KSEL; k++) {
            int e = inds[k];
            int pos = atomicAdd(&count[e], 1);
            list[e * NTOK + pos] = t;
            scalebuf[e * NTOK + pos] = sc[e] * inv;
        }
    }
}

// --- async fused gate+up GEMM, double-buffered K-loop ----------------------
__global__ __launch_bounds__(256) void gateup_kernel(
    const unsigned short* __restrict__ xbf,
    const unsigned short* __restrict__ wgb, const unsigned short* __restrict__ wub,
    const int* __restrict__ count, const int* __restrict__ list,
    const float* __restrict__ scalebuf, unsigned short* __restrict__ hbuf)
{
    int e = blockIdx.z;
    int cnt = count[e];
    int m0 = blockIdx.x * BM;
    if (m0 >= cnt) return;
    int n0 = blockIdx.y * BN;
    const unsigned short* Bg = wgb + (size_t)e * II * DD;
    const unsigned short* Bu = wub + (size_t)e * II * DD;

    __shared__ __align__(16) unsigned short As[2 * AHALF];   // 16 KB
    __shared__ __align__(16) unsigned short Bgs[2 * BHALF];  // 8 KB
    __shared__ __align__(16) unsigned short Bus[2 * BHALF];  // 8 KB
    __shared__ int rowtok[BM];

    int tid = threadIdx.x;
    if (tid < BM) {
        int gr = m0 + tid;
        rowtok[tid] = list[e * NTOK + ((gr < cnt) ? gr : 0)];
    }
    __syncthreads();

    int lane = tid & 63, wave = tid >> 6;
    int wm = wave >> 1, wn = wave & 1;
    int row16 = lane & 15, quad = lane >> 4;

    // staging geometry (chunk = 16B = 8 ushorts)
    int cA0 = (wave * 2 + 0) * 64 + lane;
    int cA1 = (wave * 2 + 1) * 64 + lane;
    int tokA0 = rowtok[cA0 >> 2], tokA1 = rowtok[cA1 >> 2];
    unsigned short* ldsA0 = As + (size_t)(wave * 2 + 0) * 512;  // wave-uniform base
    unsigned short* ldsA1 = As + (size_t)(wave * 2 + 1) * 512;
    int cB = wave * 64 + lane;
    int rB = n0 + (cB >> 2);
    unsigned short* ldsBg = Bgs + (size_t)wave * 512;
    unsigned short* ldsBu = Bus + (size_t)wave * 512;
    const unsigned short* gA0 = xbf + (size_t)tokA0 * DD + (cA0 & 3) * 8;
    const unsigned short* gA1 = xbf + (size_t)tokA1 * DD + (cA1 & 3) * 8;
    const unsigned short* gBg = Bg + (size_t)rB * DD + (cB & 3) * 8;
    const unsigned short* gBu = Bu + (size_t)rB * DD + (cB & 3) * 8;

    f32x4 accG[4][2], accU[4][2];
#pragma unroll
    for (int mi = 0; mi < 4; mi++)
#pragma unroll
        for (int ni = 0; ni < 2; ni++) {
            accG[mi][ni] = (f32x4){0.f, 0.f, 0.f, 0.f};
            accU[mi][ni] = (f32x4){0.f, 0.f, 0.f, 0.f};
        }

    // prologue: stage k0=0 into buffer 0
    gl2lds16(gA0, ldsA0);
    gl2lds16(gA1, ldsA1);
    gl2lds16(gBg, ldsBg);
    gl2lds16(gBu, ldsBu);

    int c = 0;
    for (int k0 = 0; k0 < DD; k0 += BK) {
        __syncthreads();   // drains in-flight loads into buf[c]; buf[c^1] reads done
        int nk = k0 + BK;
        if (nk < DD) {     // issue next tile into the other buffer (overlaps MFMA below)
            int bo = (c ^ 1);
            gl2lds16(gA0 + nk, ldsA0 + bo * AHALF);
            gl2lds16(gA1 + nk, ldsA1 + bo * AHALF);
            gl2lds16(gBg + nk, ldsBg + bo * BHALF);
            gl2lds16(gBu + nk, ldsBu + bo * BHALF);
        }
        const unsigned short* Ac = As + c * AHALF;
        const unsigned short* Bgc = Bgs + c * BHALF;
        const unsigned short* Buc = Bus + c * BHALF;

        bf16x8 af[4], bg[2], bu[2];
#pragma unroll
        for (int mi = 0; mi < 4; mi++)
            af[mi] = *(const bf16x8*)(Ac + (wm * 64 + mi * 16 + row16) * 32 + quad * 8);
#pragma unroll
        for (int ni = 0; ni < 2; ni++) {
            bg[ni] = *(const bf16x8*)(Bgc + (wn * 32 + ni * 16 + row16) * 32 + quad * 8);
            bu[ni] = *(const bf16x8*)(Buc + (wn * 32 + ni * 16 + row16) * 32 + quad * 8);
        }
#pragma unroll
        for (int mi = 0; mi < 4; mi++)
#pragma unroll
            for (int ni = 0; ni < 2; ni++) {
                accG[mi][ni] = __builtin_amdgcn_mfma_f32_16x16x32_bf16(af[mi], bg[ni], accG[mi][ni], 0, 0, 0);
                accU[mi][ni] = __builtin_amdgcn_mfma_f32_16x16x32_bf16(af[mi], bu[ni], accU[mi][ni], 0, 0, 0);
            }
        c ^= 1;
    }

#pragma unroll
    for (int mi = 0; mi < 4; mi++) {
        int mbase = wm * 64 + mi * 16 + quad * 4;
#pragma unroll
        for (int r = 0; r < 4; r++) {
            int gr = m0 + mbase + r;
            if (gr >= cnt) continue;
            float rs = scalebuf[e * NTOK + gr];
            size_t rowoff = ((size_t)e * NTOK + gr) * II + n0;
#pragma unroll
            for (int ni = 0; ni < 2; ni++) {
                int n = wn * 32 + ni * 16 + row16;
                float g = accG[mi][ni][r], u = accU[mi][ni][r];
                float h = g / (1.f + __expf(-g)) * u * rs;
                hbuf[rowoff + n] = f2bf(h);
            }
        }
    }
}

// --- async down GEMM, double-buffered; atomic scatter into y ---------------
__global__ __launch_bounds__(256) void down_kernel(
    const unsigned short* __restrict__ hbuf,
    const unsigned short* __restrict__ wdb,
    const int* __restrict__ count, const int* __restrict__ list,
    float* __restrict__ y)
{
    int e = blockIdx.z;
    int cnt = count[e];
    int m0 = blockIdx.x * BM;
    if (m0 >= cnt) return;
    int n0 = blockIdx.y * BN;
    const unsigned short* Bp = wdb + (size_t)e * DD * II;
    const unsigned short* Abase = hbuf + ((size_t)e * NTOK + m0) * II;

    __shared__ __align__(16) unsigned short As[2 * AHALF];
    __shared__ __align__(16) unsigned short Bs[2 * BHALF];

    int tid = threadIdx.x;
    int lane = tid & 63, wave = tid >> 6;
    int wm = wave >> 1, wn = wave & 1;
    int row16 = lane & 15, quad = lane >> 4;

    int cA0 = (wave * 2 + 0) * 64 + lane;
    int cA1 = (wave * 2 + 1) * 64 + lane;
    // rows >= cnt read stale hbuf (tiny poison-pattern bf16); results discarded.
    const unsigned short* gA0 = Abase + (size_t)(cA0 >> 2) * II + (cA0 & 3) * 8;
    const unsigned short* gA1 = Abase + (size_t)(cA1 >> 2) * II + (cA1 & 3) * 8;
    unsigned short* ldsA0 = As + (size_t)(wave * 2 + 0) * 512;
    unsigned short* ldsA1 = As + (size_t)(wave * 2 + 1) * 512;
    int cB = wave * 64 + lane;
    const unsigned short* gB = Bp + (size_t)(n0 + (cB >> 2)) * II + (cB & 3) * 8;
    unsigned short* ldsB = Bs + (size_t)wave * 512;

    f32x4 acc[4][2];
#pragma unroll
    for (int mi = 0; mi < 4; mi++)
#pragma unroll
        for (int ni = 0; ni < 2; ni++) acc[mi][ni] = (f32x4){0.f, 0.f, 0.f, 0.f};

    gl2lds16(gA0, ldsA0);
    gl2lds16(gA1, ldsA1);
    gl2lds16(gB, ldsB);

    int c = 0;
    for (int k0 = 0; k0 < II; k0 += BK) {
        __syncthreads();
        int nk = k0 + BK;
        if (nk < II) {
            int bo = (c ^ 1);
            gl2lds16(gA0 + nk, ldsA0 + bo * AHALF);
            gl2lds16(gA1 + nk, ldsA1 + bo * AHALF);
            gl2lds16(gB + nk, ldsB + bo * BHALF);
        }
        const unsigned short* Ac = As + c * AHALF;
        const unsigned short* Bc = Bs + c * BHALF;

        bf16x8 af[4], bf[2];
#pragma unroll
        for (int mi = 0; mi < 4; mi++)
            af[mi] = *(const bf16x8*)(Ac + (wm * 64 + mi * 16 + row16) * 32 + quad * 8);
#pragma unroll
        for (int ni = 0; ni < 2; ni++)
            bf[ni] = *(const bf16x8*)(Bc + (wn * 32 + ni * 16 + row16) * 32 + quad * 8);
#pragma unroll
        for (int mi = 0; mi < 4; mi++)
#pragma unroll
            for (int ni = 0; ni < 2; ni++)
                acc[mi][ni] = __builtin_amdgcn_mfma_f32_16x16x32_bf16(af[mi], bf[ni], acc[mi][ni], 0, 0, 0);
        c ^= 1;
    }

#pragma unroll
    for (int mi = 0; mi < 4; mi++) {
        int mbase = wm * 64 + mi * 16 + quad * 4;
#pragma unroll
        for (int r = 0; r < 4; r++) {
            int gr = m0 + mbase + r;
            if (gr >= cnt) continue;
            int t = list[e * NTOK + gr];
#pragma unroll
            for (int ni = 0; ni < 2; ni++) {
                int n = wn * 32 + ni * 16 + row16;
                unsafeAtomicAdd(&y[(size_t)t * DD + n0 + n], acc[mi][ni][r]);
            }
        }
    }
}

// ======================= fallback path (round-0 kernels) ====================
__global__ __launch_bounds__(256) void gateup_fb(
    const unsigned short* __restrict__ xbf,
    const float* __restrict__ wg, const float* __restrict__ wu,
    const float* __restrict__ sgw, const float* __restrict__ suw,
    const int* __restrict__ count, const int* __restrict__ list,
    const float* __restrict__ scalebuf, unsigned short* __restrict__ hbuf)
{
    int e = blockIdx.z;
    int cnt = count[e];
    int m0 = blockIdx.x * BM;
    if (m0 >= cnt) return;
    int n0 = blockIdx.y * BN;
    const float* Bg = (e < NE) ? wg + (size_t)e * II * DD : sgw;
    const float* Bu = (e < NE) ? wu + (size_t)e * II * DD : suw;

    __shared__ __align__(16) unsigned short As[BM * LDA];
    __shared__ __align__(16) unsigned short Bgs[BN * LDA];
    __shared__ __align__(16) unsigned short Bus[BN * LDA];
    __shared__ int rowtok[BM];

    int tid = threadIdx.x;
    if (tid < BM) {
        int gr = m0 + tid;
        rowtok[tid] = (gr < cnt) ? list[e * NTOK + gr] : -1;
    }
    __syncthreads();

    int lane = tid & 63, wave = tid >> 6;
    int wm = wave >> 1, wn = wave & 1;
    int row16 = lane & 15, quad = lane >> 4;

    f32x4 accG[4][2], accU[4][2];
#pragma unroll
    for (int mi = 0; mi < 4; mi++)
#pragma unroll
        for (int ni = 0; ni < 2; ni++) {
            accG[mi][ni] = (f32x4){0.f, 0.f, 0.f, 0.f};
            accU[mi][ni] = (f32x4){0.f, 0.f, 0.f, 0.f};
        }

    for (int k0 = 0; k0 < DD; k0 += BK) {
#pragma unroll
        for (int i = 0; i < 2; i++) {
            int c = tid + 256 * i;
            int row = c >> 2, kc = (c & 3) * 8;
            int tok = rowtok[row];
            uint4 v = (tok >= 0) ? *(const uint4*)(xbf + (size_t)tok * DD + k0 + kc)
                                 : make_uint4(0u, 0u, 0u, 0u);
            *(uint4*)(As + row * LDA + kc) = v;
        }
#pragma unroll
        for (int i = 0; i < 2; i++) {
            int c = tid + 256 * i;
            int row = c >> 3, f = (c & 7) * 4;
            float4 vg = *(const float4*)(Bg + (size_t)(n0 + row) * DD + k0 + f);
            float4 vu = *(const float4*)(Bu + (size_t)(n0 + row) * DD + k0 + f);
            *(ushort4*)(Bgs + row * LDA + f) = make_ushort4(f2bf(vg.x), f2bf(vg.y), f2bf(vg.z), f2bf(vg.w));
            *(ushort4*)(Bus + row * LDA + f) = make_ushort4(f2bf(vu.x), f2bf(vu.y), f2bf(vu.z), f2bf(vu.w));
        }
        __syncthreads();

        bf16x8 af[4], bg[2], bu[2];
#pragma unroll
        for (int mi = 0; mi < 4; mi++)
            af[mi] = *(const bf16x8*)(As + (wm * 64 + mi * 16 + row16) * LDA + quad * 8);
#pragma unroll
        for (int ni = 0; ni < 2; ni++) {
            bg[ni] = *(const bf16x8*)(Bgs + (wn * 32 + ni * 16 + row16) * LDA + quad * 8);
            bu[ni] = *(const bf16x8*)(Bus + (wn * 32 + ni * 16 + row16) * LDA + quad * 8);
        }
#pragma unroll
        for (int mi = 0; mi < 4; mi++)
#pragma unroll
            for (int ni = 0; ni < 2; ni++) {
                accG[mi][ni] = __builtin_amdgcn_mfma_f32_16x16x32_bf16(af[mi], bg[ni], accG[mi][ni], 0, 0, 0);
                accU[mi][ni] = __builtin_amdgcn_mfma_f32_16x16x32_bf16(af[mi], bu[ni], accU[mi][ni], 0, 0, 0);
            }
        __syncthreads();
    }

#pragma unroll
    for (int mi = 0; mi < 4; mi++) {
        int mbase = wm * 64 + mi * 16 + quad * 4;
#pragma unroll
        for (int r = 0; r < 4; r++) {
            int gr = m0 + mbase + r;
            if (gr >= cnt) continue;
            float rs = scalebuf[e * NTOK + gr];
            size_t rowoff = ((size_t)e * NTOK + gr) * II + n0;
#pragma unroll
            for (int ni = 0; ni < 2; ni++) {
                int n = wn * 32 + ni * 16 + row16;
                float g = accG[mi][ni][r], u = accU[mi][ni][r];
                float h = g / (1.f + __expf(-g)) * u * rs;
                hbuf[rowoff + n] = f2bf(h);
            }
        }
    }
}

__global__ __launch_bounds__(256) void down_fb(
    const unsigned short* __restrict__ hbuf,
    const float* __restrict__ wd, const float* __restrict__ sdw,
    const int* __restrict__ count, const int* __restrict__ list,
    float* __restrict__ y)
{
    int e = blockIdx.z;
    int cnt = count[e];
    int m0 = blockIdx.x * BM;
    if (m0 >= cnt) return;
    int n0 = blockIdx.y * BN;
    const float* Bp = (e < NE) ? wd + (size_t)e * DD * II : sdw;

    __shared__ __align__(16) unsigned short As[BM * LDA];
    __shared__ __align__(16) unsigned short Bs[BN * LDA];

    int tid = threadIdx.x;
    int lane = tid & 63, wave = tid >> 6;
    int wm = wave >> 1, wn = wave & 1;
    int row16 = lane & 15, quad = lane >> 4;

    f32x4 acc[4][2];
#pragma unroll
    for (int mi = 0; mi < 4; mi++)
#pragma unroll
        for (int ni = 0; ni < 2; ni++) acc[mi][ni] = (f32x4){0.f, 0.f, 0.f, 0.f};

    const unsigned short* Abase = hbuf + ((size_t)e * NTOK + m0) * II;

    for (int k0 = 0; k0 < II; k0 += BK) {
#pragma unroll
        for (int i = 0; i < 2; i++) {
            int c = tid + 256 * i;
            int row = c >> 2, kc = (c & 3) * 8;
            uint4 v = (m0 + row < cnt) ? *(const uint4*)(Abase + (size_t)row * II + k0 + kc)
                                       : make_uint4(0u, 0u, 0u, 0u);
            *(uint4*)(As + row * LDA + kc) = v;
        }
#pragma unroll
        for (int i = 0; i < 2; i++) {
            int c = tid + 256 * i;
            int row = c >> 3, f = (c & 7) * 4;
            float4 v = *(const float4*)(Bp + (size_t)(n0 + row) * II + k0 + f);
            *(ushort4*)(Bs + row * LDA + f) = make_ushort4(f2bf(v.x), f2bf(v.y), f2bf(v.z), f2bf(v.w));
        }
        __syncthreads();

        bf16x8 af[4], bf[2];
#pragma unroll
        for (int mi = 0; mi < 4; mi++)
            af[mi] = *(const bf16x8*)(As + (wm * 64 + mi * 16 + row16) * LDA + quad * 8);
#pragma unroll
        for (int ni = 0; ni < 2; ni++)
            bf[ni] = *(const bf16x8*)(Bs + (wn * 32 + ni * 16 + row16) * LDA + quad * 8);
#pragma unroll
        for (int mi = 0; mi < 4; mi++)
#pragma unroll
            for (int ni = 0; ni < 2; ni++)
                acc[mi][ni] = __builtin_amdgcn_mfma_f32_16x16x32_bf16(af[mi], bf[ni], acc[mi][ni], 0, 0, 0);
        __syncthreads();
    }

#pragma unroll
    for (int mi = 0; mi < 4; mi++) {
        int mbase = wm * 64 + mi * 16 + quad * 4;
#pragma unroll
        for (int r = 0; r < 4; r++) {
            int gr = m0 + mbase + r;
            if (gr >= cnt) continue;
            int t = list[e * NTOK + gr];
#pragma unroll
            for (int ni = 0; ni < 2; ni++) {
                int n = wn * 32 + ni * 16 + row16;
                unsafeAtomicAdd(&y[(size_t)t * DD + n0 + n], acc[mi][ni][r]);
            }
        }
    }
}

extern "C" void kernel_launch(void* const* d_in, const int* in_sizes, int n_in,
                              void* d_out, int out_size, void* d_ws, size_t ws_size,
                              hipStream_t stream)
{
    const float* x    = (const float*)d_in[0];
    const float* gw   = (const float*)d_in[1];
    const float* bias = (const float*)d_in[2];
    const float* wg   = (const float*)d_in[3];
    const float* wu   = (const float*)d_in[4];
    const float* wd   = (const float*)d_in[5];
    const float* sgw  = (const float*)d_in[6];
    const float* suw  = (const float*)d_in[7];
    const float* sdw  = (const float*)d_in[8];
    float* y = (float*)d_out;

    char* ws = (char*)d_ws;
    unsigned short* xbf  = (unsigned short*)(ws + OFF_XBF);
    unsigned short* hbuf = (unsigned short*)(ws + OFF_H);
    unsigned short* wgb  = (unsigned short*)(ws + OFF_WG);
    unsigned short* wub  = (unsigned short*)(ws + OFF_WU);
    unsigned short* wdb  = (unsigned short*)(ws + OFF_WD);
    int*   list     = (int*)(ws + OFF_LIST);
    float* scalebuf = (float*)(ws + OFF_SCALE);
    int*   count    = (int*)(ws + OFF_CNT);

    bool big = (ws_size >= WS_NEED);
    if (!big) {
        list     = (int*)(ws + 36ull * MB);
        scalebuf = (float*)(ws + 36ull * MB + 4ull * NEXP * NTOK);
        count    = (int*)(ws + 36ull * MB + 8ull * NEXP * NTOK);
    }

    hipMemsetAsync(d_out, 0, (size_t)NTOK * DD * sizeof(float), stream);
    hipMemsetAsync(count, 0, NEXP * sizeof(int), stream);

    prep_kernel<<<dim3(NTOK * DD / 4 / 256), 256, 0, stream>>>(x, xbf, list, scalebuf, count);
    routing_kernel<<<dim3(NTOK), 64, 0, stream>>>(x, gw, bias, count, list, scalebuf);

    if (big) {
        wconv_kernel<<<dim3((unsigned)((size_t)NEXP * II * DD / 4 / 256), 3), 256, 0, stream>>>(
            wg, wu, wd, sgw, suw, sdw, wgb, wub, wdb);
        gateup_kernel<<<dim3(NTOK / BM, II / BN, NEXP), 256, 0, stream>>>(
            xbf, wgb, wub, count, list, scalebuf, hbuf);
        down_kernel<<<dim3(NTOK / BM, DD / BN, NEXP), 256, 0, stream>>>(
            hbuf, wdb, count, list, y);
    } else {
        gateup_fb<<<dim3(NTOK / BM, II / BN, NEXP), 256, 0, stream>>>(
            xbf, wg, wu, sgw, suw, count, list, scalebuf, hbuf);
        down_fb<<<dim3(NTOK / BM, DD / BN, NEXP), 256, 0, stream>>>(
            hbuf, wd, sdw, count, list, y);
    }
}